// Round 3
// baseline (651.757 us; speedup 1.0000x reference)
//
#include <hip/hip_runtime.h>
#include <stdint.h>

// ---------------------------------------------------------------------------
// SpatialConvModule: 4-direction spatial propagation (SCNN-like) + fusion GEMM
//   R7: halo-8 decoupling. CHUNK=32 interior rows/block, 48-row extended tile
//   computed redundantly (validity shrinks 1 row/side/step); neighbor exchange
//   only every 8 steps via tagged agent-atomics (protocol identical to the
//   proven per-step one, 19x less often). Between exchanges blocks are fully
//   independent -> per-step jitter averages instead of maxing across the
//   320-stream lockstep network. 160 blocks x 512 thr: residency guaranteed.
//   Exchange buffer lives in d_out scratch (fusion overwrites it later);
//   workspace layout byte-identical to the proven 315.7MB one. fp32 xT kept:
//   numerics bit-identical (redundant halo compute is deterministic).
// ---------------------------------------------------------------------------

typedef __attribute__((ext_vector_type(8))) __bf16 bf16x8;
typedef __attribute__((ext_vector_type(4))) float f32x4;

#define DEV static __device__ __forceinline__

DEV unsigned short f2bf(float f) {
  union { float f; unsigned int u; } v; v.f = f;
  unsigned int u = v.u;
  u += 0x7fffu + ((u >> 16) & 1u);   // round-to-nearest-even
  return (unsigned short)(u >> 16);
}
DEV float bf2f(unsigned short s) {
  union { float f; unsigned int u; } v; v.u = ((unsigned int)s) << 16;
  return v.f;
}
DEV f32x4 mfma16(bf16x8 a, bf16x8 b, f32x4 c) {
  return __builtin_amdgcn_mfma_f32_16x16x32_bf16(a, b, c, 0, 0, 0);
}
// LDS-only barrier: does NOT drain vmcnt (global loads/stores stay in flight).
DEV void barrier_lds() {
  asm volatile("s_waitcnt lgkmcnt(0)\n\ts_barrier" ::: "memory");
}

constexpr int Hc = 160, Wc = 160, Cc = 128;
constexpr int CHUNK = 32, NCH = 5;   // 5 chunks of 32 interior rows
constexpr int SR = 50;               // s rows: pad + [u0-8, u0+40) + pad
constexpr int SPAD = 136;            // s row stride in bf16

// workspace layout (bytes) — identical to the proven R6 layout
constexpr long WS_XT    = 0;                         // fp32 [8][160][160][128] = 104857600
constexpr long WS_WPREP = 104857600;                 // bf16 [4][128][384]      = 393216
constexpr long WS_EPI   = 105250816;                 // float2 [512]            = 4096
constexpr long WS_FWT   = 105254912;                 // bf16 [128][512]         = 131072
constexpr long WS_FEPI  = 105385984;                 // float2 [128]            = 1024
constexpr long WS_FEAT  = 105387008;                 // bf16 [8][160][160][512] = 209715200
constexpr long WS_TOTAL = 315102208;
// exchange scratch lives in d_out (1.31MB, overwritten by fusion):
//   ex[sid][side][rr][ch] u32, sid=d*40+b*5+q (160), side 2, rr 8, ch 128
constexpr int EX_WORDS = 160 * 2 * 8 * 128;          // 327680 u32 = 1310720 B

// ---------------------------------------------------------------------------
__global__ void prep_kernel(const float* __restrict__ kern, const float* __restrict__ bias,
                            const float* __restrict__ bg, const float* __restrict__ bb,
                            const float* __restrict__ bm, const float* __restrict__ bv,
                            const float* __restrict__ fw, const float* __restrict__ fb2,
                            const float* __restrict__ fg, const float* __restrict__ fbt,
                            const float* __restrict__ fm, const float* __restrict__ fv,
                            unsigned short* __restrict__ wprep, float2* __restrict__ epi,
                            unsigned short* __restrict__ fwT, float2* __restrict__ fepi,
                            unsigned int* __restrict__ exz)
{
  int idx = blockIdx.x * 256 + threadIdx.x;
  if (idx < EX_WORDS) exz[idx] = 0;   // reset exchange tags each launch
  if (idx < 196608) {                 // wprep[d][o][t*128+c] = kmid[d][o][c][t]
    int c = idx & 127;
    int t = (idx >> 7) % 3;
    int o = (idx / 384) & 127;
    int d = idx / 49152;
    int kh = (d < 2) ? 1 : t;         // rows use k[:,:,1,:], cols use k[:,:,:,1]
    int kw = (d < 2) ? t : 1;
    wprep[idx] = f2bf(kern[(((d * 128 + o) * 128 + c) * 3 + kh) * 3 + kw]);
  }
  int i2 = idx - 196608;              // fusion weights [o][d*128+c] -> bf16
  if (i2 >= 0 && i2 < 65536) fwT[i2] = f2bf(fw[i2]);
  int i3 = idx - 262144;              // per-(d,o) BN fold: y = conv*scale + shift
  if (i3 >= 0 && i3 < 512) {
    float sc = bg[i3] / sqrtf(bv[i3] + 1e-5f);
    epi[i3] = make_float2(sc, (bias[i3] - bm[i3]) * sc + bb[i3]);
  }
  int i4 = idx - 262656;              // fusion BN fold
  if (i4 >= 0 && i4 < 128) {
    float sc = fg[i4] / sqrtf(fv[i4] + 1e-5f);
    fepi[i4] = make_float2(sc, (fb2[i4] - fm[i4]) * sc + fbt[i4]);
  }
}

// ---------------------------------------------------------------------------
__global__ void transpose_kernel(const float* __restrict__ x, float* __restrict__ xT)
{
  __shared__ float tile[32][33];
  int b = blockIdx.z, h = blockIdx.y;
  int c0 = (blockIdx.x / 5) * 32, w0 = (blockIdx.x % 5) * 32;
  int tx = threadIdx.x & 31, ty = threadIdx.x >> 5;
#pragma unroll
  for (int r = 0; r < 4; r++) {
    int c = c0 + ty + 8 * r;
    tile[ty + 8 * r][tx] = x[(((long)b * 128 + c) * 160 + h) * 160 + w0 + tx];
  }
  __syncthreads();
#pragma unroll
  for (int r = 0; r < 4; r++) {
    int w = w0 + ty + 8 * r;
    xT[(((long)b * 160 + h) * 160 + w) * 128 + c0 + tx] = tile[tx][ty + 8 * r];
  }
}

// ---------------------------------------------------------------------------
// One scan step on the 48-row extended tile. PAR = compile-time parity (t&1).
// PUB (runtime, uniform): publish the 16 boundary interior rows, tagged with
// the exchange index, for the every-8-steps neighbor exchange.
#define SCAN_STEP(T, PAR, PUB)                                                  \
  do {                                                                          \
    const int t_ = (T);                                                         \
    const int i_ = rev ? (159 - t_) : t_;                                       \
    const bool last_ = (t_ == 159);                                             \
    const unsigned short* cur_ = sbuf[PAR];                                     \
    unsigned short* nxt_ = sbuf[(PAR) ^ 1];                                     \
    /* x(i(t+1)) for this step's s-build; covered by the MFMA span */           \
    if (!last_) {                                                               \
      const float* xr_ = xb + (long)(rev ? (i_ - 1) : (i_ + 1)) * si;           \
      _Pragma("unroll") for (int m = 0; m < 3; m++)                             \
        _Pragma("unroll") for (int r = 0; r < 4; r++)                           \
          xn[m][r] = xr_[xoff[m][r]];                                           \
    }                                                                           \
    /* MFMA: 3 M-tiles x 1 N-tile, K=384: y[ydx][o] over extended tile */       \
    f32x4 acc[3];                                                               \
    acc[0] = (f32x4){0.f, 0.f, 0.f, 0.f};                                       \
    acc[1] = (f32x4){0.f, 0.f, 0.f, 0.f};                                       \
    acc[2] = (f32x4){0.f, 0.f, 0.f, 0.f};                                       \
    _Pragma("unroll") for (int kt = 0; kt < 12; kt++) {                         \
      const int tt_ = kt >> 2;                                                  \
      const int cc_ = ((kt & 3) << 5) + (kq << 3);                              \
      _Pragma("unroll") for (int m = 0; m < 3; m++) {                           \
        const bf16x8 A_ = *(const bf16x8*)&cur_[(m * 16 + ncol + tt_) * SPAD + cc_]; \
        acc[m] = mfma16(A_, Bfrag[kt], acc[m]);                                 \
      }                                                                         \
    }                                                                           \
    /* epilogue: BN fold + PReLU */                                             \
    _Pragma("unroll") for (int m = 0; m < 3; m++)                               \
      _Pragma("unroll") for (int r = 0; r < 4; r++) {                           \
        float v_ = acc[m][r] * ep.x + ep.y;                                     \
        v_ = (v_ >= 0.f) ? v_ : (aslope * v_);                                  \
        yf[m][r] = v_; yb[m][r] = f2bf(v_);                                     \
      }                                                                         \
    /* publish boundary interior rows (exchange steps only) */                  \
    if (PUB) {                                                                  \
      const unsigned int tagv_ = ((unsigned int)((t_ + 1) >> 3)) << 16;         \
      _Pragma("unroll") for (int r = 0; r < 4; r++) {                           \
        const unsigned int pv_ = (kq >= 2) ? (unsigned int)yb[0][r]             \
                                           : (unsigned int)yb[2][r];            \
        __hip_atomic_store(pubp + r * 128, tagv_ | pv_,                         \
                           __ATOMIC_RELAXED, __HIP_MEMORY_SCOPE_AGENT);         \
      }                                                                         \
    }                                                                           \
    /* s(t+1) build over the extended tile (garbage rows harmless) */           \
    if (!last_) {                                                               \
      _Pragma("unroll") for (int m = 0; m < 3; m++)                             \
        _Pragma("unroll") for (int r = 0; r < 4; r++) {                         \
          unsigned short sv_ = 0;                                               \
          if (xok[m][r]) sv_ = f2bf(xn[m][r] + yf[m][r]);                       \
          nxt_[(m * 16 + kq * 4 + r + 1) * SPAD + o] = sv_;                     \
        }                                                                       \
    }                                                                           \
    /* feat store: interior rows only (always valid) */                         \
    {                                                                           \
      unsigned short* frow_ = fbp + (long)i_ * fi;                              \
      _Pragma("unroll") for (int r = 0; r < 4; r++) {                           \
        frow_[foff0[r]] = yb[1][r];                                             \
        frow_[foff1[r]] = (kq >= 2) ? yb[0][r] : yb[2][r];                      \
      }                                                                         \
    }                                                                           \
    barrier_lds();                                                              \
  } while (0)

// Exchange fill: after the PUB step's barrier, overwrite the 8 halo rows per
// side of the freshly-built s(t+1) with x + neighbor's y (tagged spin).
#define EXCH_FILL(T, PARN)                                                      \
  do {                                                                          \
    const int tn_ = (T) + 1;                                                    \
    const unsigned int e_ = (unsigned int)(tn_ >> 3);                           \
    const int in_ = rev ? (159 - tn_) : tn_;                                    \
    unsigned short* nxt_ = sbuf[PARN];                                          \
    const float* xr_ = xb + (long)in_ * si;                                     \
    _Pragma("unroll") for (int k = 0; k < 4; k++) {                             \
      const int c_ = tid + (k << 9);                                            \
      const int side_ = c_ >> 10;                                               \
      const int rr_ = (c_ >> 7) & 7;                                            \
      const int ch_ = c_ & 127;                                                 \
      const int u_ = side_ ? (u0 + 32 + rr_) : (u0 - 8 + rr_);                  \
      const int lsp_ = side_ ? (41 + rr_) : (rr_ + 1);                          \
      unsigned short sv_ = 0;                                                   \
      if (u_ >= 0 && u_ < 160) {                                                \
        const unsigned int* slot_ = exbase +                                    \
            (long)(side_ ? (sid + 1) : (sid - 1)) * 2048 +                      \
            (((side_ ^ 1) << 3) + rr_) * 128 + ch_;                             \
        const float xv_ = xr_[u_ * su + ch_];                                   \
        unsigned int v_ = __hip_atomic_load(slot_, __ATOMIC_RELAXED,            \
                                            __HIP_MEMORY_SCOPE_AGENT);          \
        while ((v_ >> 16) != e_) {                                              \
          __builtin_amdgcn_s_sleep(1);                                          \
          v_ = __hip_atomic_load(slot_, __ATOMIC_RELAXED,                       \
                                 __HIP_MEMORY_SCOPE_AGENT);                     \
        }                                                                       \
        sv_ = f2bf(xv_ + bf2f((unsigned short)(v_ & 0xffffu)));                 \
      }                                                                         \
      nxt_[lsp_ * SPAD + ch_] = sv_;                                            \
    }                                                                           \
    barrier_lds();                                                              \
  } while (0)

// bid = q*32 + (d*8+b); chain neighbors are bid+-32 => same XCD (perf only).
__global__ __launch_bounds__(512, 1) void scan_kernel(
    const float* __restrict__ xT, const unsigned short* __restrict__ wprep,
    const float2* __restrict__ epi, const float* __restrict__ prelu_a,
    unsigned short* __restrict__ featbuf, unsigned int* exbase)
{
  __shared__ __align__(16) unsigned short sbuf[2][SR * SPAD];  // [parity][rows]

  const int bid = blockIdx.x;
  const int q = bid >> 5;            // chunk 0..4
  const int g = bid & 31;
  const int d = g >> 3;              // direction 0..3
  const int b = g & 7;               // batch
  const int tid = threadIdx.x;
  const int wv = tid >> 6;           // wave 0..7 -> N-tile
  const int lane = tid & 63;
  const int ncol = lane & 15;        // A-row / B-col / D-col lane index
  const int kq = lane >> 4;          // k-quad / D-row-quad
  const int o = wv * 16 + ncol;      // output channel
  const bool rev = (d & 1);
  const int u0 = q * CHUNK;

  const bool row_mode = (d < 2);
  const long si = row_mode ? (long)Wc * Cc : (long)Cc;   // scan-axis stride in xT
  const int  su = row_mode ? Cc : Wc * Cc;               // inner-axis stride in xT
  const long fi = row_mode ? (long)Wc * 512 : (long)512; // scan-axis stride in feat
  const int  fu = row_mode ? 512 : Wc * 512;             // inner-axis stride in feat
  const float* xb = xT + (long)b * Hc * Wc * Cc;
  unsigned short* fbp = featbuf + (long)b * Hc * Wc * 512 + d * 128;

  // B fragments: registers for all 160 steps. B[k=t*128+c][n=o].
  bf16x8 Bfrag[12];
  {
    const unsigned short* wp = wprep + ((long)(d * 128 + o)) * 384;
#pragma unroll
    for (int kt = 0; kt < 12; kt++)
      Bfrag[kt] = *(const bf16x8*)(wp + kt * 32 + kq * 8);
  }
  const float2 ep = epi[d * 128 + o];
  const float aslope = prelu_a[d];

  // loop-invariant per-cell offsets; x addresses clamped (mask at use)
  int xoff[3][4]; bool xok[3][4];
#pragma unroll
  for (int m = 0; m < 3; m++)
#pragma unroll
    for (int r = 0; r < 4; r++) {
      const int u = u0 - 8 + m * 16 + kq * 4 + r;
      const bool ok = (u >= 0 && u < 160);
      xok[m][r] = ok;
      xoff[m][r] = (ok ? u : 0) * su + o;
    }
  int foff0[4], foff1[4];
#pragma unroll
  for (int r = 0; r < 4; r++) {
    foff0[r] = (u0 + 8 + kq * 4 + r) * fu + o;                 // m=1 rows
    const int u1 = (kq >= 2) ? (u0 + (kq - 2) * 4 + r)          // m=0 rows 0..7
                             : (u0 + 24 + kq * 4 + r);          // m=2 rows 24..31
    foff1[r] = u1 * fu + o;
  }

  // exchange: sid = d*40 + b*5 + q; ex[sid][side][rr][ch]
  const int sid = d * 40 + b * 5 + q;
  unsigned int* exw = exbase + (long)sid * 2048;
  // this thread publishes 4 rows of m0 (kq>=2, side0 rr=(kq-2)*4+r)
  // or 4 rows of m2 (kq<=1, side1 rr=kq*4+r)
  unsigned int* pubp = exw + (((kq >= 2) ? (0 * 8 + (kq - 2) * 4)
                                         : (1 * 8 + kq * 4)) * 128 + o);

  // prologue: s(0) = x(i0) over all 50 rows (zeros outside domain)
  const int i0 = rev ? (Hc - 1) : 0;
  for (int e = tid; e < SR * 64; e += 512) {
    const int lsp = e >> 6, cp = e & 63;
    const int u = u0 - 9 + lsp;
    unsigned int sv = 0;
    if (u >= 0 && u < 160) {
      const float2 xv2 = *(const float2*)(xb + (long)i0 * si + (long)u * su + cp * 2);
      sv = (unsigned int)f2bf(xv2.x) | ((unsigned int)f2bf(xv2.y) << 16);
    }
    *(unsigned int*)&sbuf[0][lsp * SPAD + cp * 2] = sv;
  }
  barrier_lds();

  float yf[3][4]; unsigned short yb[3][4]; float xn[3][4];

#pragma unroll 1
  for (int t = 0; t < 160; t += 2) {
    SCAN_STEP(t, 0, false);
    const bool ex = ((t & 7) == 6) && (t != 158);
    SCAN_STEP(t + 1, 1, ex);
    if (ex) EXCH_FILL(t + 1, 0);
  }
}
#undef SCAN_STEP
#undef EXCH_FILL

// ---------------------------------------------------------------------------
__global__ __launch_bounds__(256, 1) void fusion_kernel(
    const unsigned short* __restrict__ featbuf, const unsigned short* __restrict__ fwT,
    const float2* __restrict__ fepi, float* __restrict__ out)
{
  __shared__ unsigned short At[32 * 520];   // [m][k], stride 520 (pad)
  const int bx = blockIdx.x;
  const int b = bx / 800, mb = bx - b * 800;
  const long m0 = (long)mb * 32;            // hw base within batch
  const int tid = threadIdx.x, lane = tid & 63, wv = tid >> 6;
  const int ncol = lane & 15, kq = lane >> 4;

  const unsigned short* fp = featbuf + ((long)b * 25600 + m0) * 512;
#pragma unroll
  for (int rr = 0; rr < 8; rr++) {
    const int e = tid + rr * 256;
    const int m = e >> 6, kp = e & 63;
    *(bf16x8*)&At[m * 520 + kp * 8] = *(const bf16x8*)(fp + (long)m * 512 + kp * 8);
  }
  bf16x8 Bf[2][16];
  float2 fe[2];
#pragma unroll
  for (int j = 0; j < 2; j++) {
    const int o = (wv * 2 + j) * 16 + ncol;
    const unsigned short* wp = fwT + (long)o * 512;
#pragma unroll
    for (int kt = 0; kt < 16; kt++)
      Bf[j][kt] = *(const bf16x8*)(wp + kt * 32 + kq * 8);
    fe[j] = fepi[o];
  }
  __syncthreads();

  f32x4 acc[2][2];
#pragma unroll
  for (int mt = 0; mt < 2; mt++)
#pragma unroll
    for (int j = 0; j < 2; j++)
      acc[mt][j] = (f32x4){0.f, 0.f, 0.f, 0.f};
#pragma unroll
  for (int kt = 0; kt < 16; kt++) {
    const bf16x8 A0 = *(const bf16x8*)&At[ncol * 520 + kt * 32 + kq * 8];
    const bf16x8 A1 = *(const bf16x8*)&At[(16 + ncol) * 520 + kt * 32 + kq * 8];
    acc[0][0] = mfma16(A0, Bf[0][kt], acc[0][0]);
    acc[0][1] = mfma16(A0, Bf[1][kt], acc[0][1]);
    acc[1][0] = mfma16(A1, Bf[0][kt], acc[1][0]);
    acc[1][1] = mfma16(A1, Bf[1][kt], acc[1][1]);
  }
#pragma unroll
  for (int mt = 0; mt < 2; mt++)
#pragma unroll
    for (int j = 0; j < 2; j++) {
      const int o = (wv * 2 + j) * 16 + ncol;
      const long hw = m0 + mt * 16 + kq * 4;
      f32x4 v;
#pragma unroll
      for (int r = 0; r < 4; r++) {
        const float z = acc[mt][j][r] * fe[j].x + fe[j].y;
        v[r] = (z > 0.f) ? z : 0.f;
      }
      *(f32x4*)(out + ((long)(b * 128 + o)) * 25600 + hw) = v;  // NCHW, float4
    }
}

// ---------------------------------------------------------------------------
extern "C" void kernel_launch(void* const* d_in, const int* in_sizes, int n_in,
                              void* d_out, int out_size, void* d_ws, size_t ws_size,
                              hipStream_t stream)
{
  if (ws_size < (size_t)WS_TOTAL) return;  // fail visibly rather than corrupt

  const float* x        = (const float*)d_in[0];
  const float* kernels  = (const float*)d_in[1];
  const float* biases   = (const float*)d_in[2];
  const float* bn_gamma = (const float*)d_in[3];
  const float* bn_beta  = (const float*)d_in[4];
  const float* bn_mean  = (const float*)d_in[5];
  const float* bn_var   = (const float*)d_in[6];
  const float* prelu_a  = (const float*)d_in[7];
  const float* fus_w    = (const float*)d_in[8];
  const float* fus_b    = (const float*)d_in[9];
  const float* fbn_g    = (const float*)d_in[10];
  const float* fbn_b    = (const float*)d_in[11];
  const float* fbn_m    = (const float*)d_in[12];
  const float* fbn_v    = (const float*)d_in[13];

  char* ws = (char*)d_ws;
  float*          xT      = (float*)(ws + WS_XT);
  unsigned short* wprep   = (unsigned short*)(ws + WS_WPREP);
  float2*         epi     = (float2*)(ws + WS_EPI);
  unsigned short* fwT     = (unsigned short*)(ws + WS_FWT);
  float2*         fepi    = (float2*)(ws + WS_FEPI);
  unsigned short* featbuf = (unsigned short*)(ws + WS_FEAT);
  unsigned int*   ex      = (unsigned int*)d_out;   // scratch; fusion overwrites
  float*          out     = (float*)d_out;

  prep_kernel<<<1280, 256, 0, stream>>>(kernels, biases, bn_gamma, bn_beta, bn_mean, bn_var,
                                        fus_w, fus_b, fbn_g, fbn_b, fbn_m, fbn_v,
                                        wprep, epi, fwT, fepi, ex);
  transpose_kernel<<<dim3(20, 160, 8), 256, 0, stream>>>(x, xT);
  scan_kernel<<<160, 512, 0, stream>>>(xT, wprep, epi, prelu_a, featbuf, ex);
  fusion_kernel<<<6400, 256, 0, stream>>>(featbuf, fwT, fepi, out);
}

// Round 4
// 568.541 us; speedup vs baseline: 1.1464x; 1.1464x over previous
//
#include <hip/hip_runtime.h>
#include <stdint.h>

// ---------------------------------------------------------------------------
// SpatialConvModule: 4-direction spatial propagation (SCNN-like) + fusion GEMM
//   R8: halo-6 decoupling + 2-way A-reuse (fixes R7's LDS-pipe bound).
//   - CHUNK=20 interior rows, ext tile 32 rows = 2 M-tiles. 8 waves =
//     (m 0/1) x (ng 0..3); each wave: 1 M-tile x 2 N-tiles -> every A
//     ds_read_b128 feeds 2 MFMA (R7: 1). LDS reads/block-step: 288 -> 96.
//   - Exchange every 6 steps (tagged agent-atomics, protocol as R7-passed).
//   - 4 dir x 8 batch x 8 chunks = 256 blocks x 512 thr: <= 1 block/CU
//     feasible everywhere => all blocks resident => spin cannot deadlock.
//   - Exchange buffer in d_out scratch (fusion overwrites later).
// ---------------------------------------------------------------------------

typedef __attribute__((ext_vector_type(8))) __bf16 bf16x8;
typedef __attribute__((ext_vector_type(4))) float f32x4;

#define DEV static __device__ __forceinline__

DEV unsigned short f2bf(float f) {
  union { float f; unsigned int u; } v; v.f = f;
  unsigned int u = v.u;
  u += 0x7fffu + ((u >> 16) & 1u);   // round-to-nearest-even
  return (unsigned short)(u >> 16);
}
DEV float bf2f(unsigned short s) {
  union { float f; unsigned int u; } v; v.u = ((unsigned int)s) << 16;
  return v.f;
}
DEV f32x4 mfma16(bf16x8 a, bf16x8 b, f32x4 c) {
  return __builtin_amdgcn_mfma_f32_16x16x32_bf16(a, b, c, 0, 0, 0);
}
// LDS-only barrier: does NOT drain vmcnt (global loads/stores stay in flight).
DEV void barrier_lds() {
  asm volatile("s_waitcnt lgkmcnt(0)\n\ts_barrier" ::: "memory");
}

constexpr int Hc = 160, Wc = 160, Cc = 128;
constexpr int CHUNK = 20, NCH = 8;   // 8 chunks of 20 interior rows
constexpr int HALO = 6;              // exchange every 6 steps
constexpr int SR = 34;               // pad + ext[0..31] + pad
constexpr int SPAD = 136;            // s row stride in bf16

// workspace layout (bytes) — identical to the proven layout
constexpr long WS_XT    = 0;                         // fp32 [8][160][160][128] = 104857600
constexpr long WS_WPREP = 104857600;                 // bf16 [4][128][384]      = 393216
constexpr long WS_EPI   = 105250816;                 // float2 [512]            = 4096
constexpr long WS_FWT   = 105254912;                 // bf16 [128][512]         = 131072
constexpr long WS_FEPI  = 105385984;                 // float2 [128]            = 1024
constexpr long WS_FEAT  = 105387008;                 // bf16 [8][160][160][512] = 209715200
constexpr long WS_TOTAL = 315102208;
// exchange scratch in d_out (fusion overwrites it):
//   ex[sid][side][rr<6][ch<128] u32, sid = (d*8+b)*8+q (256 sids)
constexpr int EX_STRIDE = 2 * 6 * 128;               // 1536 words per sid
constexpr int EX_WORDS  = 256 * EX_STRIDE;           // 393216 u32 = 1.57 MB

// ---------------------------------------------------------------------------
__global__ void prep_kernel(const float* __restrict__ kern, const float* __restrict__ bias,
                            const float* __restrict__ bg, const float* __restrict__ bb,
                            const float* __restrict__ bm, const float* __restrict__ bv,
                            const float* __restrict__ fw, const float* __restrict__ fb2,
                            const float* __restrict__ fg, const float* __restrict__ fbt,
                            const float* __restrict__ fm, const float* __restrict__ fv,
                            unsigned short* __restrict__ wprep, float2* __restrict__ epi,
                            unsigned short* __restrict__ fwT, float2* __restrict__ fepi,
                            unsigned int* __restrict__ exz)
{
  int idx = blockIdx.x * 256 + threadIdx.x;
  if (idx < EX_WORDS) exz[idx] = 0;   // reset exchange tags each launch
  if (idx < 196608) {                 // wprep[d][o][t*128+c] = kmid[d][o][c][t]
    int c = idx & 127;
    int t = (idx >> 7) % 3;
    int o = (idx / 384) & 127;
    int d = idx / 49152;
    int kh = (d < 2) ? 1 : t;         // rows use k[:,:,1,:], cols use k[:,:,:,1]
    int kw = (d < 2) ? t : 1;
    wprep[idx] = f2bf(kern[(((d * 128 + o) * 128 + c) * 3 + kh) * 3 + kw]);
  }
  int i2 = idx - 196608;              // fusion weights [o][d*128+c] -> bf16
  if (i2 >= 0 && i2 < 65536) fwT[i2] = f2bf(fw[i2]);
  int i3 = idx - 262144;              // per-(d,o) BN fold: y = conv*scale + shift
  if (i3 >= 0 && i3 < 512) {
    float sc = bg[i3] / sqrtf(bv[i3] + 1e-5f);
    epi[i3] = make_float2(sc, (bias[i3] - bm[i3]) * sc + bb[i3]);
  }
  int i4 = idx - 262656;              // fusion BN fold
  if (i4 >= 0 && i4 < 128) {
    float sc = fg[i4] / sqrtf(fv[i4] + 1e-5f);
    fepi[i4] = make_float2(sc, (fb2[i4] - fm[i4]) * sc + fbt[i4]);
  }
}

// ---------------------------------------------------------------------------
__global__ void transpose_kernel(const float* __restrict__ x, float* __restrict__ xT)
{
  __shared__ float tile[32][33];
  int b = blockIdx.z, h = blockIdx.y;
  int c0 = (blockIdx.x / 5) * 32, w0 = (blockIdx.x % 5) * 32;
  int tx = threadIdx.x & 31, ty = threadIdx.x >> 5;
#pragma unroll
  for (int r = 0; r < 4; r++) {
    int c = c0 + ty + 8 * r;
    tile[ty + 8 * r][tx] = x[(((long)b * 128 + c) * 160 + h) * 160 + w0 + tx];
  }
  __syncthreads();
#pragma unroll
  for (int r = 0; r < 4; r++) {
    int w = w0 + ty + 8 * r;
    xT[(((long)b * 160 + h) * 160 + w) * 128 + c0 + tx] = tile[tx][ty + 8 * r];
  }
}

// ---------------------------------------------------------------------------
// One scan step on the 32-row extended tile. PAR = compile-time parity (t&1).
// PUB (uniform runtime): publish the 6 boundary interior rows per side with
// tag 'exidx' for the every-6-steps exchange.
#define SCAN_STEP(T, PAR, PUB)                                                  \
  do {                                                                          \
    const int t_ = (T);                                                         \
    const int i_ = rev ? (159 - t_) : t_;                                       \
    const bool last_ = (t_ == 159);                                             \
    const unsigned short* cur_ = sbuf[PAR];                                     \
    unsigned short* nxt_ = sbuf[(PAR) ^ 1];                                     \
    /* x(i(t+1)) for this step's s-build (covered by the MFMA span) */          \
    if (!last_) {                                                               \
      const float* xr_ = xb + (long)(rev ? (i_ - 1) : (i_ + 1)) * si;           \
      _Pragma("unroll") for (int j = 0; j < 2; j++)                             \
        _Pragma("unroll") for (int r = 0; r < 4; r++)                           \
          xn[j][r] = xr_[xoff[r] + 16 * j];                                     \
    }                                                                           \
    /* MFMA: 1 M-tile x 2 N-tiles, K=384; each A-read feeds 2 MFMA */           \
    f32x4 acc0_ = {0.f, 0.f, 0.f, 0.f}, acc1_ = {0.f, 0.f, 0.f, 0.f};           \
    _Pragma("unroll") for (int kt = 0; kt < 12; kt++) {                         \
      const int tt_ = kt >> 2;                                                  \
      const int cc_ = ((kt & 3) << 5) + (kq << 3);                              \
      const bf16x8 A_ = *(const bf16x8*)&cur_[(m * 16 + ncol + tt_) * SPAD + cc_]; \
      acc0_ = mfma16(A_, Bfrag[0][kt], acc0_);                                  \
      acc1_ = mfma16(A_, Bfrag[1][kt], acc1_);                                  \
    }                                                                           \
    /* epilogue: BN fold + PReLU */                                             \
    _Pragma("unroll") for (int r = 0; r < 4; r++) {                             \
      float v0_ = acc0_[r] * ep[0].x + ep[0].y;                                 \
      v0_ = (v0_ >= 0.f) ? v0_ : (aslope * v0_);                                \
      yf[0][r] = v0_; yb[0][r] = f2bf(v0_);                                     \
      float v1_ = acc1_[r] * ep[1].x + ep[1].y;                                 \
      v1_ = (v1_ >= 0.f) ? v1_ : (aslope * v1_);                                \
      yf[1][r] = v1_; yb[1][r] = f2bf(v1_);                                     \
    }                                                                           \
    /* publish boundary interior rows (exchange steps only) */                  \
    if (PUB) {                                                                  \
      const unsigned int tagv_ = ((unsigned int)exidx) << 16;                   \
      _Pragma("unroll") for (int r = 0; r < 4; r++)                             \
        if (pok[r]) {                                                           \
          __hip_atomic_store(exw + pubidx[r], tagv_ | (unsigned int)yb[0][r],   \
                             __ATOMIC_RELAXED, __HIP_MEMORY_SCOPE_AGENT);       \
          __hip_atomic_store(exw + pubidx[r] + 16, tagv_ | (unsigned int)yb[1][r], \
                             __ATOMIC_RELAXED, __HIP_MEMORY_SCOPE_AGENT);       \
        }                                                                       \
    }                                                                           \
    /* s(t+1) build over the extended tile (out-of-domain rows -> 0) */         \
    if (!last_) {                                                               \
      _Pragma("unroll") for (int j = 0; j < 2; j++)                             \
        _Pragma("unroll") for (int r = 0; r < 4; r++) {                         \
          unsigned short sv_ = 0;                                               \
          if (xok[r]) sv_ = f2bf(xn[j][r] + yf[j][r]);                          \
          nxt_[(m * 16 + kq * 4 + r + 1) * SPAD + o0 + 16 * j] = sv_;           \
        }                                                                       \
    }                                                                           \
    /* feat store: interior rows only (fire-and-forget vmem) */                 \
    {                                                                           \
      unsigned short* frow_ = fbp + (long)i_ * fi;                              \
      _Pragma("unroll") for (int j = 0; j < 2; j++)                             \
        _Pragma("unroll") for (int r = 0; r < 4; r++)                           \
          if (fok[r]) frow_[foff[r] + 16 * j] = yb[j][r];                       \
    }                                                                           \
    barrier_lds();                                                              \
  } while (0)

// Exchange fill: after the PUB step's barrier, overwrite the 6 halo rows per
// side of the freshly-built s(t+1) with x + neighbor's y (tagged spin).
#define EXCH_FILL(T)                                                            \
  do {                                                                          \
    const int tn_ = (T) + 1;                                                    \
    const int in_ = rev ? (159 - tn_) : tn_;                                    \
    unsigned short* nxt_ = sbuf[0];  /* T is odd -> next buffer is parity 0 */  \
    const float* xr_ = xb + (long)in_ * si;                                     \
    _Pragma("unroll") for (int k = 0; k < 3; k++) {                             \
      const int c_ = tid + (k << 9);             /* 1536 cells / 512 thr */     \
      const int side_ = (c_ >= 768);                                            \
      const int idx_ = side_ ? (c_ - 768) : c_;                                 \
      const int rr_ = idx_ >> 7;                                                \
      const int ch_ = idx_ & 127;                                               \
      const int u_ = side_ ? (u0 + 20 + rr_) : (u0 - 6 + rr_);                  \
      const int lsp_ = side_ ? (27 + rr_) : (1 + rr_);                          \
      unsigned short sv_ = 0;                                                   \
      if (u_ >= 0 && u_ < 160) {                                                \
        const unsigned int* slot_ = exbase +                                    \
            (long)(side_ ? (sid + 1) : (sid - 1)) * EX_STRIDE +                 \
            (((side_ ^ 1) * 6) + rr_) * 128 + ch_;                              \
        const float xv_ = xr_[u_ * su + ch_];                                   \
        unsigned int v_ = __hip_atomic_load(slot_, __ATOMIC_RELAXED,            \
                                            __HIP_MEMORY_SCOPE_AGENT);          \
        while ((v_ >> 16) != (unsigned int)exidx) {                             \
          __builtin_amdgcn_s_sleep(1);                                          \
          v_ = __hip_atomic_load(slot_, __ATOMIC_RELAXED,                       \
                                 __HIP_MEMORY_SCOPE_AGENT);                     \
        }                                                                       \
        sv_ = f2bf(xv_ + bf2f((unsigned short)(v_ & 0xffffu)));                 \
      }                                                                         \
      nxt_[lsp_ * SPAD + ch_] = sv_;                                            \
    }                                                                           \
    exidx++;                                                                    \
    barrier_lds();                                                              \
  } while (0)

// bid = q*32 + (d*8+b); chain neighbors are bid+-32 => same XCD (perf only).
__global__ __launch_bounds__(512, 1) void scan_kernel(
    const float* __restrict__ xT, const unsigned short* __restrict__ wprep,
    const float2* __restrict__ epi, const float* __restrict__ prelu_a,
    unsigned short* __restrict__ featbuf, unsigned int* exbase)
{
  __shared__ __align__(16) unsigned short sbuf[2][SR * SPAD];  // [parity][rows]

  const int bid = blockIdx.x;
  const int q = bid >> 5;            // chunk 0..7
  const int g = bid & 31;
  const int d = g >> 3;              // direction 0..3
  const int b = g & 7;               // batch
  const int tid = threadIdx.x;
  const int wv = tid >> 6;           // wave 0..7
  const int m = wv >> 2;             // M-tile 0/1 (ext rows m*16..m*16+15)
  const int ng = wv & 3;             // 32-channel group
  const int lane = tid & 63;
  const int ncol = lane & 15;        // A-row / B-col / D-col lane index
  const int kq = lane >> 4;          // k-quad / D-row-quad
  const int o0 = ng * 32 + ncol;     // j=0 channel; j=1 adds +16
  const bool rev = (d & 1);
  const int u0 = q * CHUNK;

  const bool row_mode = (d < 2);
  const long si = row_mode ? (long)Wc * Cc : (long)Cc;   // scan-axis stride in xT
  const int  su = row_mode ? Cc : Wc * Cc;               // inner-axis stride in xT
  const long fi = row_mode ? (long)Wc * 512 : (long)512; // scan-axis stride in feat
  const int  fu = row_mode ? 512 : Wc * 512;             // inner-axis stride in feat
  const float* xb = xT + (long)b * Hc * Wc * Cc;
  unsigned short* fbp = featbuf + (long)b * Hc * Wc * 512 + d * 128;

  // B fragments: registers for all 160 steps. B[k=t*128+c][n=o].
  bf16x8 Bfrag[2][12];
  float2 ep[2];
#pragma unroll
  for (int j = 0; j < 2; j++) {
    const int o = o0 + 16 * j;
    const unsigned short* wp = wprep + ((long)(d * 128 + o)) * 384;
#pragma unroll
    for (int kt = 0; kt < 12; kt++)
      Bfrag[j][kt] = *(const bf16x8*)(wp + kt * 32 + kq * 8);
    ep[j] = epi[d * 128 + o];
  }
  const float aslope = prelu_a[d];

  // per-r geometry: ext row = m*16 + kq*4 + r; interior = ext in [6,26)
  int xoff[4]; bool xok[4];
  int foff[4]; bool fok[4];
  int pubidx[4]; bool pok[4];
#pragma unroll
  for (int r = 0; r < 4; r++) {
    const int ext = m * 16 + kq * 4 + r;
    const int u = u0 - 6 + ext;
    xok[r] = (u >= 0 && u < 160);
    xoff[r] = (xok[r] ? u : 0) * su + o0;
    fok[r] = (ext >= 6 && ext < 26);
    foff[r] = (fok[r] ? u : 0) * fu + o0;
    if (ext >= 6 && ext < 12)       { pok[r] = true;  pubidx[r] = (ext - 6) * 128 + o0; }
    else if (ext >= 20 && ext < 26) { pok[r] = true;  pubidx[r] = (6 + ext - 20) * 128 + o0; }
    else                            { pok[r] = false; pubidx[r] = 0; }
  }

  // exchange: sid = (d*8+b)*8 + q
  const int sid = (d * 8 + b) * 8 + q;
  unsigned int* exw = exbase + (long)sid * EX_STRIDE;

  // prologue: s(0) = x(i0) over all 34 rows (zeros outside domain)
  const int i0 = rev ? (Hc - 1) : 0;
  for (int e = tid; e < SR * 64; e += 512) {
    const int lsp = e >> 6, cp = e & 63;
    const int u = u0 - 7 + lsp;
    unsigned int sv = 0;
    if (u >= 0 && u < 160) {
      const float2 xv2 = *(const float2*)(xb + (long)i0 * si + (long)u * su + cp * 2);
      sv = (unsigned int)f2bf(xv2.x) | ((unsigned int)f2bf(xv2.y) << 16);
    }
    *(unsigned int*)&sbuf[0][lsp * SPAD + cp * 2] = sv;
  }
  barrier_lds();

  float yf[2][4]; unsigned short yb[2][4]; float xn[2][4];
  int exidx = 1;

#pragma unroll 1
  for (int tb = 0; tb < 160; tb += 2) {
    SCAN_STEP(tb, 0, false);
    const bool ex = (((tb + 1) % 6) == 5);   // T = 5,11,...,155 (all odd)
    SCAN_STEP(tb + 1, 1, ex);
    if (ex) EXCH_FILL(tb + 1);
  }
}
#undef SCAN_STEP
#undef EXCH_FILL

// ---------------------------------------------------------------------------
__global__ __launch_bounds__(256, 1) void fusion_kernel(
    const unsigned short* __restrict__ featbuf, const unsigned short* __restrict__ fwT,
    const float2* __restrict__ fepi, float* __restrict__ out)
{
  __shared__ unsigned short At[32 * 520];   // [m][k], stride 520 (pad)
  const int bx = blockIdx.x;
  const int b = bx / 800, mb = bx - b * 800;
  const long m0 = (long)mb * 32;            // hw base within batch
  const int tid = threadIdx.x, lane = tid & 63, wv = tid >> 6;
  const int ncol = lane & 15, kq = lane >> 4;

  const unsigned short* fp = featbuf + ((long)b * 25600 + m0) * 512;
#pragma unroll
  for (int rr = 0; rr < 8; rr++) {
    const int e = tid + rr * 256;
    const int m = e >> 6, kp = e & 63;
    *(bf16x8*)&At[m * 520 + kp * 8] = *(const bf16x8*)(fp + (long)m * 512 + kp * 8);
  }
  bf16x8 Bf[2][16];
  float2 fe[2];
#pragma unroll
  for (int j = 0; j < 2; j++) {
    const int o = (wv * 2 + j) * 16 + ncol;
    const unsigned short* wp = fwT + (long)o * 512;
#pragma unroll
    for (int kt = 0; kt < 16; kt++)
      Bf[j][kt] = *(const bf16x8*)(wp + kt * 32 + kq * 8);
    fe[j] = fepi[o];
  }
  __syncthreads();

  f32x4 acc[2][2];
#pragma unroll
  for (int mt = 0; mt < 2; mt++)
#pragma unroll
    for (int j = 0; j < 2; j++)
      acc[mt][j] = (f32x4){0.f, 0.f, 0.f, 0.f};
#pragma unroll
  for (int kt = 0; kt < 16; kt++) {
    const bf16x8 A0 = *(const bf16x8*)&At[ncol * 520 + kt * 32 + kq * 8];
    const bf16x8 A1 = *(const bf16x8*)&At[(16 + ncol) * 520 + kt * 32 + kq * 8];
    acc[0][0] = mfma16(A0, Bf[0][kt], acc[0][0]);
    acc[0][1] = mfma16(A0, Bf[1][kt], acc[0][1]);
    acc[1][0] = mfma16(A1, Bf[0][kt], acc[1][0]);
    acc[1][1] = mfma16(A1, Bf[1][kt], acc[1][1]);
  }
#pragma unroll
  for (int mt = 0; mt < 2; mt++)
#pragma unroll
    for (int j = 0; j < 2; j++) {
      const int o = (wv * 2 + j) * 16 + ncol;
      const long hw = m0 + mt * 16 + kq * 4;
      f32x4 v;
#pragma unroll
      for (int r = 0; r < 4; r++) {
        const float z = acc[mt][j][r] * fe[j].x + fe[j].y;
        v[r] = (z > 0.f) ? z : 0.f;
      }
      *(f32x4*)(out + ((long)(b * 128 + o)) * 25600 + hw) = v;  // NCHW, float4
    }
}

// ---------------------------------------------------------------------------
extern "C" void kernel_launch(void* const* d_in, const int* in_sizes, int n_in,
                              void* d_out, int out_size, void* d_ws, size_t ws_size,
                              hipStream_t stream)
{
  if (ws_size < (size_t)WS_TOTAL) return;  // fail visibly rather than corrupt

  const float* x        = (const float*)d_in[0];
  const float* kernels  = (const float*)d_in[1];
  const float* biases   = (const float*)d_in[2];
  const float* bn_gamma = (const float*)d_in[3];
  const float* bn_beta  = (const float*)d_in[4];
  const float* bn_mean  = (const float*)d_in[5];
  const float* bn_var   = (const float*)d_in[6];
  const float* prelu_a  = (const float*)d_in[7];
  const float* fus_w    = (const float*)d_in[8];
  const float* fus_b    = (const float*)d_in[9];
  const float* fbn_g    = (const float*)d_in[10];
  const float* fbn_b    = (const float*)d_in[11];
  const float* fbn_m    = (const float*)d_in[12];
  const float* fbn_v    = (const float*)d_in[13];

  char* ws = (char*)d_ws;
  float*          xT      = (float*)(ws + WS_XT);
  unsigned short* wprep   = (unsigned short*)(ws + WS_WPREP);
  float2*         epi     = (float2*)(ws + WS_EPI);
  unsigned short* fwT     = (unsigned short*)(ws + WS_FWT);
  float2*         fepi    = (float2*)(ws + WS_FEPI);
  unsigned short* featbuf = (unsigned short*)(ws + WS_FEAT);
  unsigned int*   ex      = (unsigned int*)d_out;   // scratch; fusion overwrites
  float*          out     = (float*)d_out;

  prep_kernel<<<1536, 256, 0, stream>>>(kernels, biases, bn_gamma, bn_beta, bn_mean, bn_var,
                                        fus_w, fus_b, fbn_g, fbn_b, fbn_m, fbn_v,
                                        wprep, epi, fwT, fepi, ex);
  transpose_kernel<<<dim3(20, 160, 8), 256, 0, stream>>>(x, xT);
  scan_kernel<<<256, 512, 0, stream>>>(xT, wprep, epi, prelu_a, featbuf, ex);
  fusion_kernel<<<6400, 256, 0, stream>>>(featbuf, fwT, fepi, out);
}